// Round 5
// baseline (280.993 us; speedup 1.0000x reference)
//
#include <hip/hip_runtime.h>
#include <hip/hip_bf16.h>
#include <cstdint>
#include <cstddef>

#define D_MODEL 1024
#define SEQ     2048
#define BATCH   8
#define M_TOT   (BATCH*SEQ)     // 16384
#define N_TOT   (3*D_MODEL)     // 3072
#define K_TOT   D_MODEL         // 1024
#define KTILES  (K_TOT/64)      // 16
#define NCH     32              // scan chunks
#define LCH     (SEQ/NCH)       // 64 steps emitted per chunk
#define W_UP    16              // warmup steps (carry decays ~0.1^16)

typedef unsigned short u16;
typedef __attribute__((ext_vector_type(8))) short short8;
typedef __attribute__((ext_vector_type(4))) float f32x4;

__device__ __forceinline__ u16 f2bf(float f) {
    __hip_bfloat16 h = __float2bfloat16(f);   // RNE
    return __builtin_bit_cast(u16, h);
}
__device__ __forceinline__ float bf2f(u16 u) {
    __hip_bfloat16 h = __builtin_bit_cast(__hip_bfloat16, u);
    return __bfloat162float(h);
}
__device__ __forceinline__ float sigmoidf(float v) {
    return 1.0f / (1.0f + __expf(-v));
}
__device__ __forceinline__ void gld_lds16(const void* g, void* l) {
    __builtin_amdgcn_global_load_lds((const __attribute__((address_space(1))) void*)g,
                                     (__attribute__((address_space(3))) void*)l, 16, 0, 0);
}
// raw barrier with compiler-level memory fence (NOT __syncthreads: that drains vmcnt(0))
__device__ __forceinline__ void wg_barrier() {
    asm volatile("" ::: "memory");
    __builtin_amdgcn_s_barrier();
    asm volatile("" ::: "memory");
}

// ---------------------------------------------------------------------------
// Merged converts: blocks 0..511  : x (fp32)->xb (bf16) + column-sum for SToken
//                  blocks 512..3583: W_B|W_C|W_d (fp32)->wcat (bf16 [3072,1024])
__global__ void k_convert(const float* __restrict__ x, u16* __restrict__ xb,
                          float* __restrict__ sq,
                          const float* __restrict__ WB, const float* __restrict__ WC,
                          const float* __restrict__ Wd, u16* __restrict__ wcat) {
    int bid = blockIdx.x;
    if (bid < 512) {
        int tblk = bid & 15, dblk = (bid >> 4) & 3, b = bid >> 6;
        int d = dblk * 256 + threadIdx.x;
        size_t base = ((size_t)b * SEQ + (size_t)tblk * 128) * D_MODEL + d;
        float sum = 0.f;
        for (int t = 0; t < 128; ++t) {
            float v = x[base + (size_t)t * D_MODEL];
            sum += v;
            xb[base + (size_t)t * D_MODEL] = f2bf(v);
        }
        atomicAdd(&sq[b * D_MODEL + d], sum);
    } else {
        int tg = (bid - 512) * 256 + threadIdx.x;
        size_t e0 = (size_t)tg * 4;
        int n = (int)(e0 >> 10), k0 = (int)(e0 & 1023);
        const float* W = (n < 1024) ? (WB + (size_t)n * 1024)
                       : (n < 2048) ? (WC + (size_t)(n - 1024) * 1024)
                                    : (Wd + (size_t)(n - 2048) * 1024);
        float4 v = *(const float4*)&W[k0];
        wcat[e0 + 0] = f2bf(v.x);
        wcat[e0 + 1] = f2bf(v.y);
        wcat[e0 + 2] = f2bf(v.z);
        wcat[e0 + 3] = f2bf(v.w);
    }
}

// stv[b,n] = sigmoid(relu( (sq[b,:]/L) @ W_st[n,:] + b_st[n] ))
__global__ void k_stoken(const float* __restrict__ sq, const float* __restrict__ Wst,
                         const float* __restrict__ bst, float* __restrict__ stv) {
    __shared__ float s[D_MODEL];
    int b = blockIdx.x >> 2, nblk = blockIdx.x & 3;
    for (int i = threadIdx.x; i < D_MODEL; i += 256)
        s[i] = sq[b * D_MODEL + i] * (1.0f / SEQ);
    __syncthreads();
    int n = nblk * 256 + threadIdx.x;
    const float* w = Wst + (size_t)n * D_MODEL;
    float acc = 0.f;
    for (int k = 0; k < D_MODEL; k += 4) {
        float4 wv = *(const float4*)&w[k];
        acc += s[k] * wv.x + s[k+1] * wv.y + s[k+2] * wv.z + s[k+3] * wv.w;
    }
    acc += bst[n];
    acc = fmaxf(acc, 0.f);
    stv[b * D_MODEL + n] = sigmoidf(acc);
}

// ---------------------------------------------------------------------------
// 256x256-tile bf16 GEMM (B^T form).  A goes through LDS (real reuse: each
// A byte read by 4 same-wM waves); B-operand fragments load DIRECTLY from
// global to VGPRs (B is 6.3 MB, L2/L3-hot; LDS staging bought nothing and
// LDS bandwidth was co-critical with MFMA).  LDS: 64 KiB = 2 buf x 2 kk x
// [256 rows x 32 k] bf16, A only.  One barrier + one vmcnt(0) per K-tile;
// stage(t+1) targets buf^1 whose readers are a barrier behind (r4 proof).
// Slab swizzle (involution, 16B-slot):  p ^= ((p>>7)&3)<<4 — pre-swizzled
// global source (linear LDS dest, rule #21) + swizzled ds_read address.
// ---------------------------------------------------------------------------
__device__ __forceinline__ u16* slab_ptr(u16* ls, int buf, int kk) {
    return ls + (size_t)((buf << 1) | kk) * 8192;
}

__device__ __forceinline__ short8 ldsfrag(const u16* slab, int R, int g) {
    int off = R * 64 + ((g ^ ((R >> 1) & 3)) << 4);   // bytes, swizzled
    return *(const short8*)((const char*)slab + off);
}

__device__ __forceinline__ void stage_a(const u16* __restrict__ A,
                                        u16* ls, int buf, int kk, int ktile,
                                        int i0, int w, int l) {
    // stages A-slab(kk) of K-tile `ktile` into `buf`: 16 KiB, 2 loads/thread.
    int srow = l >> 2;                                // 0..15
    int scol = ((l & 3) ^ ((l >> 3) & 3)) << 4;       // pre-swizzled source byte
    int kbyte = (ktile * 64 + kk * 32) * 2;
    u16* la = slab_ptr(ls, buf, kk);
#pragma unroll
    for (int j = 0; j < 2; ++j) {
        int s = 2 * w + j;                            // slice 0..15 (1 KiB each)
        int row = s * 16 + srow;
        gld_lds16((const char*)(A + (size_t)(i0 + row) * K_TOT) + kbyte + scol,
                  (char*)la + s * 1024);
    }
}

template<bool SG>
__device__ __forceinline__ void kgroup(const u16* __restrict__ A, const u16* __restrict__ Bm,
                                       u16* ls, int t, int i0, int n0,
                                       int wM, int wN, int w, int l, int r, int g,
                                       f32x4 acc[8][4]) {
    const int buf = t & 1;
    const int RA = wM * 128 + r;

    asm volatile("s_waitcnt vmcnt(0)" ::: "memory");   // stage(t) done (queue cold)
    wg_barrier();                                      // publish; t-1 readers done

    // B fragments for this tile: direct global->VGPR (same bytes/lanes as the
    // old LDS path).  Issued first so the A-DMA below stays behind them in
    // the vmcnt queue (b0 use -> vmcnt(8), b1 -> vmcnt(4): DMA never drained).
    short8 b0[4], b1[4];
    const u16* bp = Bm + (size_t)(n0 + wN * 64 + r) * K_TOT + t * 64 + g * 8;
#pragma unroll
    for (int n = 0; n < 4; ++n) b0[n] = *(const short8*)(bp + (size_t)n * 16 * K_TOT);
#pragma unroll
    for (int n = 0; n < 4; ++n) b1[n] = *(const short8*)(bp + (size_t)n * 16 * K_TOT + 32);

    if (SG) {
        stage_a(A, ls, buf ^ 1, 0, t + 1, i0, w, l);
        stage_a(A, ls, buf ^ 1, 1, t + 1, i0, w, l);
    }

    const u16* As0 = slab_ptr(ls, buf, 0);
    const u16* As1 = slab_ptr(ls, buf, 1);
    short8 a0[4], a1[4];

#pragma unroll
    for (int m = 0; m < 4; ++m) a0[m] = ldsfrag(As0, RA + m * 16, g);
#pragma unroll
    for (int m = 0; m < 4; ++m) a1[m] = ldsfrag(As1, RA + m * 16, g);

    __builtin_amdgcn_s_setprio(1);
#pragma unroll
    for (int m = 0; m < 4; ++m)
#pragma unroll
        for (int n = 0; n < 4; ++n)
            acc[m][n] = __builtin_amdgcn_mfma_f32_16x16x32_bf16(a0[m], b0[n], acc[m][n], 0, 0, 0);
    __builtin_amdgcn_s_setprio(0);

#pragma unroll
    for (int m = 0; m < 4; ++m) a0[m] = ldsfrag(As0, RA + 64 + m * 16, g);   // kk0 hi

    __builtin_amdgcn_s_setprio(1);
#pragma unroll
    for (int m = 0; m < 4; ++m)
#pragma unroll
        for (int n = 0; n < 4; ++n)
            acc[m][n] = __builtin_amdgcn_mfma_f32_16x16x32_bf16(a1[m], b1[n], acc[m][n], 0, 0, 0);
    __builtin_amdgcn_s_setprio(0);

#pragma unroll
    for (int m = 0; m < 4; ++m) a1[m] = ldsfrag(As1, RA + 64 + m * 16, g);   // kk1 hi

    __builtin_amdgcn_s_setprio(1);
#pragma unroll
    for (int m = 0; m < 4; ++m)
#pragma unroll
        for (int n = 0; n < 4; ++n)
            acc[4 + m][n] = __builtin_amdgcn_mfma_f32_16x16x32_bf16(a0[m], b0[n], acc[4 + m][n], 0, 0, 0);
#pragma unroll
    for (int m = 0; m < 4; ++m)
#pragma unroll
        for (int n = 0; n < 4; ++n)
            acc[4 + m][n] = __builtin_amdgcn_mfma_f32_16x16x32_bf16(a1[m], b1[n], acc[4 + m][n], 0, 0, 0);
    __builtin_amdgcn_s_setprio(0);
}

__global__ __launch_bounds__(512, 2) void k_gemm(const u16* __restrict__ A,
                                                 const u16* __restrict__ Bm,
                                                 u16* __restrict__ Cout) {
    __shared__ u16 ls[4 * 8192];   // 64 KiB, A only
    const int tid = threadIdx.x;
    const int l = tid & 63, w = tid >> 6;
    const int wM = w >> 2, wN = w & 3;
    const int r = l & 15, g = l >> 4;
    const int i0 = blockIdx.y * 256;
    const int n0 = blockIdx.x * 256;

    f32x4 acc[8][4] = {};

    // prologue: stage A-tile 0 into buf0
    stage_a(A, ls, 0, 0, 0, i0, w, l);
    stage_a(A, ls, 0, 1, 0, i0, w, l);

    for (int t = 0; t < KTILES - 1; ++t)
        kgroup<true>(A, Bm, ls, t, i0, n0, wM, wN, w, l, r, g, acc);
    kgroup<false>(A, Bm, ls, KTILES - 1, i0, n0, wM, wN, w, l, r, g, acc);

    // epilogue: C/D layout col=lane&15, row=(lane>>4)*4+j  [HW-verified]
#pragma unroll
    for (int mi = 0; mi < 8; ++mi)
#pragma unroll
        for (int n = 0; n < 4; ++n)
#pragma unroll
            for (int j = 0; j < 4; ++j) {
                size_t row = (size_t)(i0 + wM * 128 + mi * 16 + g * 4 + j);
                size_t col = (size_t)(n0 + wN * 64 + n * 16 + r);
                Cout[row * N_TOT + col] = f2bf(acc[mi][n][j]);
            }
}

// ---------------------------------------------------------------------------
// Single-pass chunked scan with warmup overlap.  |a_t| = sigmoid*|A| <~ 0.1,
// so a 16-step warmup bounds carry-truncation error by ~1e-16 — exact for
// chunk 0.  Each thread owns 2 d-channels (float2 / packed-bf16 loads).
__global__ void k_scan(const float* __restrict__ x, const u16* __restrict__ g3,
                       const float* __restrict__ dp, const float* __restrict__ Aar,
                       const float* __restrict__ bB, const float* __restrict__ bC,
                       const float* __restrict__ bd, const float* __restrict__ stv,
                       const float* __restrict__ stb, float* __restrict__ out) {
    int bid = blockIdx.x;
    int dblk = bid & 1, c = (bid >> 1) & (NCH - 1), b = bid >> 6;
    int d = dblk * 512 + threadIdx.x * 2;

    float2 bBv = *(const float2*)&bB[d];
    float2 bdv = *(const float2*)&bd[d];
    float2 bCv = *(const float2*)&bC[d];
    float2 stvv = *(const float2*)&stv[b * D_MODEL + d];
    float2 stbv = *(const float2*)&stb[d];
    float tc0 = stvv.x + stbv.x, tc1 = stvv.y + stbv.y;

    int t0 = c * LCH;
    int tw = (c == 0) ? 0 : t0 - W_UP;
    float s0 = 0.f, s1 = 0.f;

    size_t xoff = ((size_t)b * SEQ + tw) * D_MODEL + d;
    size_t goff = ((size_t)b * SEQ + tw) * N_TOT + d;
    size_t poff = (size_t)tw * D_MODEL + d;

    for (int t = tw; t < t0; ++t) {
        float2 xv = *(const float2*)&x[xoff];
        uint gB = *(const uint*)&g3[goff];
        uint gd = *(const uint*)&g3[goff + 2048];
        float2 dpv = *(const float2*)&dp[poff];
        float2 Av  = *(const float2*)&Aar[poff];
        float b00 = bf2f((u16)(gB & 0xffff)) + bBv.x;
        float b01 = bf2f((u16)(gB >> 16)) + bBv.y;
        float de0 = sigmoidf(bf2f((u16)(gd & 0xffff)) + bdv.x + dpv.x);
        float de1 = sigmoidf(bf2f((u16)(gd >> 16)) + bdv.y + dpv.y);
        s0 = de0 * Av.x * s0 + de0 * b00 * xv.x;
        s1 = de1 * Av.y * s1 + de1 * b01 * xv.y;
        xoff += D_MODEL; goff += N_TOT; poff += D_MODEL;
    }
    for (int t = t0; t < t0 + LCH; ++t) {
        float2 xv = *(const float2*)&x[xoff];
        uint gB = *(const uint*)&g3[goff];
        uint gC = *(const uint*)&g3[goff + 1024];
        uint gd = *(const uint*)&g3[goff + 2048];
        float2 dpv = *(const float2*)&dp[poff];
        float2 Av  = *(const float2*)&Aar[poff];
        float b00 = bf2f((u16)(gB & 0xffff)) + bBv.x;
        float b01 = bf2f((u16)(gB >> 16)) + bBv.y;
        float de0 = sigmoidf(bf2f((u16)(gd & 0xffff)) + bdv.x + dpv.x);
        float de1 = sigmoidf(bf2f((u16)(gd >> 16)) + bdv.y + dpv.y);
        s0 = de0 * Av.x * s0 + de0 * b00 * xv.x;
        s1 = de1 * Av.y * s1 + de1 * b01 * xv.y;
        float c0 = bf2f((u16)(gC & 0xffff)) + bCv.x;
        float c1 = bf2f((u16)(gC >> 16)) + bCv.y;
        float y0 = (c0 * s0 + tc0 * xv.x) * sigmoidf(xv.x);
        float y1 = (c1 * s1 + tc1 * xv.y) * sigmoidf(xv.y);
        *(float2*)&out[xoff] = make_float2(y0, y1);
        xoff += D_MODEL; goff += N_TOT; poff += D_MODEL;
    }
}

// ---------------------------------------------------------------------------
extern "C" void kernel_launch(void* const* d_in, const int* in_sizes, int n_in,
                              void* d_out, int out_size, void* d_ws, size_t ws_size,
                              hipStream_t stream) {
    const float* x    = (const float*)d_in[0];
    const float* W_B  = (const float*)d_in[1];
    const float* b_B  = (const float*)d_in[2];
    const float* W_C  = (const float*)d_in[3];
    const float* b_C  = (const float*)d_in[4];
    const float* W_d  = (const float*)d_in[5];
    const float* b_d  = (const float*)d_in[6];
    const float* dp   = (const float*)d_in[7];
    const float* Aar  = (const float*)d_in[8];
    const float* W_st = (const float*)d_in[9];
    const float* b_st = (const float*)d_in[10];
    const float* stb  = (const float*)d_in[11];
    float* out = (float*)d_out;

    char* ws = (char*)d_ws;
    u16* xb   = (u16*)ws;  ws += (size_t)M_TOT * K_TOT * 2;   // 33.5 MB
    u16* wcat = (u16*)ws;  ws += (size_t)N_TOT * K_TOT * 2;   //  6.3 MB
    u16* g3   = (u16*)ws;  ws += (size_t)M_TOT * N_TOT * 2;   // 100.7 MB
    float* sq   = (float*)ws; ws += (size_t)BATCH * D_MODEL * 4;
    float* stv  = (float*)ws; ws += (size_t)BATCH * D_MODEL * 4;

    hipMemsetAsync(sq, 0, (size_t)BATCH * D_MODEL * 4, stream);
    k_convert<<<3584, 256, 0, stream>>>(x, xb, sq, W_B, W_C, W_d, wcat);
    k_stoken<<<32, 256, 0, stream>>>(sq, W_st, b_st, stv);
    k_gemm<<<dim3(N_TOT / 256, M_TOT / 256), 512, 0, stream>>>(xb, wcat, g3);
    k_scan<<<512, 256, 0, stream>>>(x, g3, dp, Aar, b_B, b_C, b_d, stv, stb, out);
}